// Round 18
// baseline (150.831 us; speedup 1.0000x reference)
//
#include <hip/hip_runtime.h>

// ---------------------------------------------------------------------------
// BetterGooLayer R18: single fused kernel, scan-wave specialization.
// R17 post-mortem: 64.8us, WRITE=own bytes (traffic minimal), VALU 43% —
// compute/serialization-bound. Biggest waste: 64-chunk scan run identically
// by all 16 waves (~670 ops/thread). R18: 2 chains per barrier-pair; wave 0
// scans chain A, wave 1 chain B into s0L (others skip); rec split
// rec += mm*acc0 (walk1) - mm*k*ex (correction) frees fq after walk1 ->
// full next-pair prefetch fits in regs. gtap/pad hoisted to start.
// Math identical to R17 modulo benign re-association (absmax ~16).
// ---------------------------------------------------------------------------

#define NS    8192
#define BB    4
#define MM    64
#define DD    8
#define NF    8
#define FL    256
#define DAMP  0.9998f

#define REC_OFF  0
#define DISP_OFF (BB*MM*NS)                 // 2097152
#define HF_OFF   (DISP_OFF + BB*MM*DD*NS)   // 18874368

#define SW(i) ((i) + ((i) >> 5))

struct Mat { float a, b, c, d; };
__device__ __forceinline__ Mat matmul(Mat x, Mat y) {
    Mat r;
    r.a = fmaf(x.a, y.a, x.b * y.c);
    r.b = fmaf(x.a, y.b, x.b * y.d);
    r.c = fmaf(x.c, y.a, x.d * y.c);
    r.d = fmaf(x.c, y.b, x.d * y.d);
    return r;
}

// ---------------- threefry2x32 (JAX, partitionable counters) ----------------
__device__ __forceinline__ unsigned rotl32(unsigned x, int r) {
    return (x << r) | (x >> (32 - r));
}
__device__ float jax_noise(unsigned idx) {
    const unsigned ks0 = 0u;
    const unsigned ks1 = 123u;
    const unsigned ks2 = 0x1BD11BDAu ^ 0u ^ 123u;
    unsigned x0 = 0u  + ks0;
    unsigned x1 = idx + ks1;
#define TF_RND(r) { x0 += x1; x1 = rotl32(x1, r); x1 ^= x0; }
    TF_RND(13) TF_RND(15) TF_RND(26) TF_RND(6)
    x0 += ks1; x1 += ks2 + 1u;
    TF_RND(17) TF_RND(29) TF_RND(16) TF_RND(24)
    x0 += ks2; x1 += ks0 + 2u;
    TF_RND(13) TF_RND(15) TF_RND(26) TF_RND(6)
    x0 += ks0; x1 += ks1 + 3u;
    TF_RND(17) TF_RND(29) TF_RND(16) TF_RND(24)
    x0 += ks1; x1 += ks2 + 4u;
    TF_RND(13) TF_RND(15) TF_RND(26) TF_RND(6)
    x0 += ks2; x1 += ks0 + 5u;
#undef TF_RND
    unsigned bits = x0 ^ x1;
    float u = __uint_as_float((bits >> 9) | 0x3f800000u) - 1.0f;  // [0,1)
    return fmaxf(-0.01f, u * 0.02f - 0.01f);
}

// ---------------- fused everything: block = bm, 1024 threads ----------------
__global__ __launch_bounds__(1024, 4) void sim_all(
    const float* __restrict__ forces, const float* __restrict__ hm,
    const float* __restrict__ home,   const float* __restrict__ cs,
    const float* __restrict__ masses, const float* __restrict__ tens,
    const float* __restrict__ mics,
    const float* __restrict__ filters, const float* __restrict__ tfm,
    const float* __restrict__ bias,    const float* __restrict__ hf_gain,
    float* __restrict__ out)
{
    __shared__ float up[SW(FL + NS) + 8];   // ~34.8 KB noise window
    __shared__ float gtap[FL];
    __shared__ float2 qcL[2][64];
    __shared__ float2 s0L[2][64];

    int bm   = blockIdx.x;
    int tid  = threadIdx.x;
    int sub  = tid & 15;            // position within 16-thread chunk group
    int m    = bm & (MM - 1);

    float ms  = masses[m];
    float csm = cs[m];

    // early independent work: FIR taps + left pad (overlaps first loads)
    if (tid < FL) {
        up[SW(tid)] = 0.f;
        int b = bm >> 6;
        float gs = 0.f;
#pragma unroll
        for (int f = 0; f < NF; ++f) {
            float mix = 0.f;
#pragma unroll
            for (int dd = 0; dd < DD; ++dd)
                mix = fmaf(bias[m * DD + dd], tfm[(m * DD + dd) * NF + f], mix);
            gs = fmaf(mix, filters[(b * NF + f) * FL + tid], gs);
        }
        gtap[tid] = gs;
    }

    size_t chbase = (size_t)(bm * DD) * NS + tid * 8;
    float rec_acc[8] = {0, 0, 0, 0, 0, 0, 0, 0};

    // prologue: pair 0 (chains 0,1)
    float4 fqA[2], hqA[2], fqB[2], hqB[2];
    fqA[0] = *(const float4*)(forces + chbase);
    fqA[1] = *(const float4*)(forces + chbase + 4);
    hqA[0] = *(const float4*)(hm + chbase);
    hqA[1] = *(const float4*)(hm + chbase + 4);
    fqB[0] = *(const float4*)(forces + chbase + NS);
    fqB[1] = *(const float4*)(forces + chbase + NS + 4);
    hqB[0] = *(const float4*)(hm + chbase + NS);
    hqB[1] = *(const float4*)(hm + chbase + NS + 4);

    for (int it = 0; it < 4; ++it) {
        int dA = 2 * it, dB = 2 * it + 1;
        float kA  = tens[m * DD + dA] / ms;
        float kB  = tens[m * DD + dB] / ms;
        float hdA = home[dA], hdB = home[dB];
        float mmA = ms * mics[m * DD + dA];
        float mmB = ms * mics[m * DD + dB];
        size_t gA = chbase + (size_t)dA * NS;
        size_t gB = chbase + (size_t)dB * NS;

        // ---- walk1 A (u-form); rec += mmA*acc0; h,f die after ----
        float dir0A[8];
        {
            const float* fr = (const float*)fqA;
            const float* hr = (const float*)hqA;
            float pos = 0.f, vel = 0.f;
#pragma unroll
            for (int j = 0; j < 8; ++j) {
                float ht = fmaf(hr[j], csm, hdA);
                float u  = fmaf(kA, ht, fr[j]);
                dir0A[j] = ht - pos;
                float w  = fmaf(-kA, pos, u);             // acc0
                rec_acc[j] = fmaf(mmA, w, rec_acc[j]);
                vel = (vel + w) * DAMP;
                pos += vel;
            }
            fqA[0].x = pos; fqA[0].y = vel;   // stash (Wx,Wy) in dead reg
        }
        // ---- walk1 B ----
        float dir0B[8];
        {
            const float* fr = (const float*)fqB;
            const float* hr = (const float*)hqB;
            float pos = 0.f, vel = 0.f;
#pragma unroll
            for (int j = 0; j < 8; ++j) {
                float ht = fmaf(hr[j], csm, hdB);
                float u  = fmaf(kB, ht, fr[j]);
                dir0B[j] = ht - pos;
                float w  = fmaf(-kB, pos, u);
                rec_acc[j] = fmaf(mmB, w, rec_acc[j]);
                vel = (vel + w) * DAMP;
                pos += vel;
            }
            fqB[0].x = pos; fqB[0].y = vel;
        }

        // ---- prefetch next pair (f/h regs mostly dead now) ----
        float4 nfA0, nfA1, nhA0, nhA1, nfB0, nfB1, nhB0, nhB1;
        if (it < 3) {
            size_t gnA = gA + 2 * NS, gnB = gB + 2 * NS;
            nfA0 = *(const float4*)(forces + gnA);
            nfA1 = *(const float4*)(forces + gnA + 4);
            nhA0 = *(const float4*)(hm + gnA);
            nhA1 = *(const float4*)(hm + gnA + 4);
            nfB0 = *(const float4*)(forces + gnB);
            nfB1 = *(const float4*)(forces + gnB + 4);
            nhB0 = *(const float4*)(hm + gnB);
            nhB1 = *(const float4*)(hm + gnB + 4);
        }

        // ---- matrices + group KS, chain A ----
        Mat AA = {1.f - DAMP * kA, DAMP, -DAMP * kA, DAMP};
        Mat PA;
        float ExA, EyA;
        {
            Mat A2 = matmul(AA, AA);
            Mat A4 = matmul(A2, A2);
            Mat G0 = matmul(A4, A4);
            Mat G1 = matmul(G0, G0);
            Mat G2 = matmul(G1, G1);
            Mat G3 = matmul(G2, G2);
            Mat P = {1.f, 0.f, 0.f, 1.f};
            if (sub & 1) P = matmul(P, G0);
            if (sub & 2) P = matmul(P, G1);
            if (sub & 4) P = matmul(P, G2);
            if (sub & 8) P = matmul(P, G3);
            PA = P;
            float Wx = fqA[0].x, Wy = fqA[0].y;
            float ox, oy;
            ox = __shfl_up(Wx, 1, 64); oy = __shfl_up(Wy, 1, 64);
            if (sub >= 1) { float nx = Wx + fmaf(G0.a, ox, G0.b * oy);
                            float ny = Wy + fmaf(G0.c, ox, G0.d * oy);
                            Wx = nx; Wy = ny; }
            ox = __shfl_up(Wx, 2, 64); oy = __shfl_up(Wy, 2, 64);
            if (sub >= 2) { float nx = Wx + fmaf(G1.a, ox, G1.b * oy);
                            float ny = Wy + fmaf(G1.c, ox, G1.d * oy);
                            Wx = nx; Wy = ny; }
            ox = __shfl_up(Wx, 4, 64); oy = __shfl_up(Wy, 4, 64);
            if (sub >= 4) { float nx = Wx + fmaf(G2.a, ox, G2.b * oy);
                            float ny = Wy + fmaf(G2.c, ox, G2.d * oy);
                            Wx = nx; Wy = ny; }
            ox = __shfl_up(Wx, 8, 64); oy = __shfl_up(Wy, 8, 64);
            if (sub >= 8) { float nx = Wx + fmaf(G3.a, ox, G3.b * oy);
                            float ny = Wy + fmaf(G3.c, ox, G3.d * oy);
                            Wx = nx; Wy = ny; }
            ExA = __shfl_up(Wx, 1, 64);
            EyA = __shfl_up(Wy, 1, 64);
            if (sub == 0) { ExA = 0.f; EyA = 0.f; }
            if (sub == 15) qcL[0][tid >> 4] = make_float2(Wx, Wy);
        }
        // ---- matrices + group KS, chain B ----
        Mat AB = {1.f - DAMP * kB, DAMP, -DAMP * kB, DAMP};
        Mat PB;
        float ExB, EyB;
        {
            Mat A2 = matmul(AB, AB);
            Mat A4 = matmul(A2, A2);
            Mat G0 = matmul(A4, A4);
            Mat G1 = matmul(G0, G0);
            Mat G2 = matmul(G1, G1);
            Mat G3 = matmul(G2, G2);
            Mat P = {1.f, 0.f, 0.f, 1.f};
            if (sub & 1) P = matmul(P, G0);
            if (sub & 2) P = matmul(P, G1);
            if (sub & 4) P = matmul(P, G2);
            if (sub & 8) P = matmul(P, G3);
            PB = P;
            float Wx = fqB[0].x, Wy = fqB[0].y;
            float ox, oy;
            ox = __shfl_up(Wx, 1, 64); oy = __shfl_up(Wy, 1, 64);
            if (sub >= 1) { float nx = Wx + fmaf(G0.a, ox, G0.b * oy);
                            float ny = Wy + fmaf(G0.c, ox, G0.d * oy);
                            Wx = nx; Wy = ny; }
            ox = __shfl_up(Wx, 2, 64); oy = __shfl_up(Wy, 2, 64);
            if (sub >= 2) { float nx = Wx + fmaf(G1.a, ox, G1.b * oy);
                            float ny = Wy + fmaf(G1.c, ox, G1.d * oy);
                            Wx = nx; Wy = ny; }
            ox = __shfl_up(Wx, 4, 64); oy = __shfl_up(Wy, 4, 64);
            if (sub >= 4) { float nx = Wx + fmaf(G2.a, ox, G2.b * oy);
                            float ny = Wy + fmaf(G2.c, ox, G2.d * oy);
                            Wx = nx; Wy = ny; }
            ox = __shfl_up(Wx, 8, 64); oy = __shfl_up(Wy, 8, 64);
            if (sub >= 8) { float nx = Wx + fmaf(G3.a, ox, G3.b * oy);
                            float ny = Wy + fmaf(G3.c, ox, G3.d * oy);
                            Wx = nx; Wy = ny; }
            ExB = __shfl_up(Wx, 1, 64);
            EyB = __shfl_up(Wy, 1, 64);
            if (sub == 0) { ExB = 0.f; EyB = 0.f; }
            if (sub == 15) qcL[1][tid >> 4] = make_float2(Wx, Wy);
        }

        __syncthreads();

        // ---- chunk scans: wave 0 -> chain A, wave 1 -> chain B ----
        if (tid < 128) {
            int c    = tid >> 6;
            int lane = tid & 63;
            float kc = c ? kB : kA;
            Mat Bm = {1.f - DAMP * kc, DAMP, -DAMP * kc, DAMP};
#pragma unroll
            for (int i = 0; i < 7; ++i) Bm = matmul(Bm, Bm);   // A^128
            float2 qv = qcL[c][lane];
            float sx = qv.x, sy = qv.y;
            Mat Kr = Bm;
#pragma unroll
            for (int r = 0; r < 6; ++r) {
                float ox = __shfl_up(sx, 1 << r, 64);
                float oy = __shfl_up(sy, 1 << r, 64);
                if (lane >= (1 << r)) {
                    float nx = fmaf(Kr.a, ox, fmaf(Kr.b, oy, sx));
                    float ny = fmaf(Kr.c, ox, fmaf(Kr.d, oy, sy));
                    sx = nx; sy = ny;
                }
                if (r < 5) Kr = matmul(Kr, Kr);
            }
            float px = __shfl_up(sx, 1, 64);
            float py = __shfl_up(sy, 1, 64);
            if (lane == 0) { px = 0.f; py = 0.f; }
            s0L[c][lane] = make_float2(px, py);
        }
        __syncthreads();

        // ---- corrections ----
        {
            float2 sv = s0L[0][tid >> 4];
            float ex = fmaf(PA.a, sv.x, fmaf(PA.b, sv.y, ExA));
            float ey = fmaf(PA.c, sv.x, fmaf(PA.d, sv.y, EyA));
            float mmk = mmA * kA;
#pragma unroll
            for (int q = 0; q < 2; ++q) {
                float dv[4];
#pragma unroll
                for (int i = 0; i < 4; ++i) {
                    int j = q * 4 + i;
                    dv[i] = dir0A[j] - ex;
                    rec_acc[j] = fmaf(-mmk, ex, rec_acc[j]);
                    float nx = fmaf(AA.a, ex, AA.b * ey);
                    float ny = fmaf(AA.c, ex, AA.d * ey);
                    ex = nx; ey = ny;
                }
                *(float4*)(out + DISP_OFF + gA + q * 4) =
                    make_float4(dv[0], dv[1], dv[2], dv[3]);
            }
        }
        {
            float2 sv = s0L[1][tid >> 4];
            float ex = fmaf(PB.a, sv.x, fmaf(PB.b, sv.y, ExB));
            float ey = fmaf(PB.c, sv.x, fmaf(PB.d, sv.y, EyB));
            float mmk = mmB * kB;
#pragma unroll
            for (int q = 0; q < 2; ++q) {
                float dv[4];
#pragma unroll
                for (int i = 0; i < 4; ++i) {
                    int j = q * 4 + i;
                    dv[i] = dir0B[j] - ex;
                    rec_acc[j] = fmaf(-mmk, ex, rec_acc[j]);
                    float nx = fmaf(AB.a, ex, AB.b * ey);
                    float ny = fmaf(AB.c, ex, AB.d * ey);
                    ex = nx; ey = ny;
                }
                *(float4*)(out + DISP_OFF + gB + q * 4) =
                    make_float4(dv[0], dv[1], dv[2], dv[3]);
            }
        }

        if (it < 3) {
            fqA[0] = nfA0; fqA[1] = nfA1;
            hqA[0] = nhA0; hqA[1] = nhA1;
            fqB[0] = nfB0; fqB[1] = nfB1;
            hqB[0] = nhB0; hqB[1] = nhB1;
        }
    }

    // ---- rec output + noise window ----
    size_t rowbase = (size_t)bm * NS + tid * 8;
    *(float4*)(out + REC_OFF + rowbase) =
        make_float4(rec_acc[0], rec_acc[1], rec_acc[2], rec_acc[3]);
    *(float4*)(out + REC_OFF + rowbase + 4) =
        make_float4(rec_acc[4], rec_acc[5], rec_acc[6], rec_acc[7]);

    int t0 = tid * 8;
#pragma unroll
    for (int i = 0; i < 8; ++i) {
        float nz = jax_noise((unsigned)(bm * NS + t0 + i));
        up[SW(FL + t0 + i)] = fabsf(rec_acc[i]) * nz;
    }
    __syncthreads();

    // ---- FIR: 8 outputs per thread, register sliding window ----
    float gain = hf_gain[0];
    float acc[8] = {0, 0, 0, 0, 0, 0, 0, 0};
    float w[8];
#pragma unroll
    for (int j = 0; j < 8; ++j) w[j] = up[SW(t0 + 1 + j)];
#pragma unroll 8
    for (int s = 255; s >= 1; --s) {
        float gv = gtap[s];
#pragma unroll
        for (int j = 0; j < 8; ++j) acc[j] = fmaf(gv, w[j], acc[j]);
#pragma unroll
        for (int j = 0; j < 7; ++j) w[j] = w[j + 1];
        w[7] = up[SW(FL + t0 + 8 - s)];
    }
    float g0 = gtap[0];
#pragma unroll
    for (int j = 0; j < 8; ++j) acc[j] = fmaf(g0, w[j], acc[j]);
    float4 o0 = make_float4(fmaf(gain, acc[0], rec_acc[0]),
                            fmaf(gain, acc[1], rec_acc[1]),
                            fmaf(gain, acc[2], rec_acc[2]),
                            fmaf(gain, acc[3], rec_acc[3]));
    float4 o1 = make_float4(fmaf(gain, acc[4], rec_acc[4]),
                            fmaf(gain, acc[5], rec_acc[5]),
                            fmaf(gain, acc[6], rec_acc[6]),
                            fmaf(gain, acc[7], rec_acc[7]));
    *(float4*)(out + HF_OFF + rowbase)     = o0;
    *(float4*)(out + HF_OFF + rowbase + 4) = o1;
}

extern "C" void kernel_launch(void* const* d_in, const int* in_sizes, int n_in,
                              void* d_out, int out_size, void* d_ws, size_t ws_size,
                              hipStream_t stream)
{
    const float* forces  = (const float*)d_in[0];
    const float* hm      = (const float*)d_in[1];
    const float* filters = (const float*)d_in[2];
    const float* home    = (const float*)d_in[3];
    const float* cs      = (const float*)d_in[4];
    const float* masses  = (const float*)d_in[5];
    const float* tens    = (const float*)d_in[6];
    const float* mics    = (const float*)d_in[7];
    const float* tfm     = (const float*)d_in[8];
    const float* bias    = (const float*)d_in[9];
    const float* gain    = (const float*)d_in[10];
    float* out = (float*)d_out;

    sim_all<<<BB * MM, 1024, 0, stream>>>(
        forces, hm, home, cs, masses, tens, mics,
        filters, tfm, bias, gain, out);
}

// Round 19
// 74.328 us; speedup vs baseline: 2.0293x; 2.0293x over previous
//
#include <hip/hip_runtime.h>

// ---------------------------------------------------------------------------
// BetterGooLayer R19: occupancy split — 2 blocks per bm.
// R18 post-mortem: pairing+prefetch spilled (VGPR 64 vs ~100 live; FETCH/WRITE
// ballooned) — reverted to R17's proven per-chain body (48 VGPR, no spill).
// R17 residual: 1 block/CU, 16 waves, 9 barriers -> barrier serialization at
// 36% occupancy. R19: grid 512 = (bm, half); block owns 4 chains; rec partial
// (4 chains) in registers -> part row (16 MB, L3-resident); separate FIR
// kernel sums 2 partials. 2 blocks/CU -> 32 waves/CU, barrier stalls overlap.
// ---------------------------------------------------------------------------

#define NS    8192
#define BB    4
#define MM    64
#define DD    8
#define NF    8
#define FL    256
#define DAMP  0.9998f
#define SEG   2048

#define REC_OFF  0
#define DISP_OFF (BB*MM*NS)                 // 2097152
#define HF_OFF   (DISP_OFF + BB*MM*DD*NS)   // 18874368

#define SW(i) ((i) + ((i) >> 5))

struct Mat { float a, b, c, d; };
__device__ __forceinline__ Mat matmul(Mat x, Mat y) {
    Mat r;
    r.a = fmaf(x.a, y.a, x.b * y.c);
    r.b = fmaf(x.a, y.b, x.b * y.d);
    r.c = fmaf(x.c, y.a, x.d * y.c);
    r.d = fmaf(x.c, y.b, x.d * y.d);
    return r;
}

// ---------------- threefry2x32 (JAX, partitionable counters) ----------------
__device__ __forceinline__ unsigned rotl32(unsigned x, int r) {
    return (x << r) | (x >> (32 - r));
}
__device__ float jax_noise(unsigned idx) {
    const unsigned ks0 = 0u;
    const unsigned ks1 = 123u;
    const unsigned ks2 = 0x1BD11BDAu ^ 0u ^ 123u;
    unsigned x0 = 0u  + ks0;
    unsigned x1 = idx + ks1;
#define TF_RND(r) { x0 += x1; x1 = rotl32(x1, r); x1 ^= x0; }
    TF_RND(13) TF_RND(15) TF_RND(26) TF_RND(6)
    x0 += ks1; x1 += ks2 + 1u;
    TF_RND(17) TF_RND(29) TF_RND(16) TF_RND(24)
    x0 += ks2; x1 += ks0 + 2u;
    TF_RND(13) TF_RND(15) TF_RND(26) TF_RND(6)
    x0 += ks0; x1 += ks1 + 3u;
    TF_RND(17) TF_RND(29) TF_RND(16) TF_RND(24)
    x0 += ks1; x1 += ks2 + 4u;
    TF_RND(13) TF_RND(15) TF_RND(26) TF_RND(6)
    x0 += ks2; x1 += ks0 + 5u;
#undef TF_RND
    unsigned bits = x0 ^ x1;
    float u = __uint_as_float((bits >> 9) | 0x3f800000u) - 1.0f;  // [0,1)
    return fmaxf(-0.01f, u * 0.02f - 0.01f);
}

// ---------------- sim: block = (bm, half), 4 chains, 1024 threads -----------
__global__ __launch_bounds__(1024, 4) void sim_half(
    const float* __restrict__ forces, const float* __restrict__ hm,
    const float* __restrict__ home,   const float* __restrict__ cs,
    const float* __restrict__ masses, const float* __restrict__ tens,
    const float* __restrict__ mics,   float* __restrict__ out,
    float* __restrict__ part)
{
    __shared__ float2 qcL[2][64];

    int bh   = blockIdx.x;          // bm*2 + half
    int bm   = bh >> 1;
    int half = bh & 1;
    int tid  = threadIdx.x;
    int sub  = tid & 15;
    int m    = bm & (MM - 1);

    float ms  = masses[m];
    float csm = cs[m];

    size_t chbase = (size_t)(bm * DD + half * 4) * NS + tid * 8;
    float rec_acc[8] = {0, 0, 0, 0, 0, 0, 0, 0};

    // prologue: first chain loads
    float4 fq[2], hq[2];
    fq[0] = *(const float4*)(forces + chbase);
    fq[1] = *(const float4*)(forces + chbase + 4);
    hq[0] = *(const float4*)(hm + chbase);
    hq[1] = *(const float4*)(hm + chbase + 4);

    for (int dit = 0; dit < 4; ++dit) {
        int d = half * 4 + dit;
        float k   = tens[m * DD + d] / ms;
        float hd  = home[d];
        float mm_ = ms * mics[m * DD + d];
        size_t gbase = chbase + (size_t)dit * NS;

        const float* fr = (const float*)fq;
        const float* hr = (const float*)hq;

        // walk1 from zero state (u-form), capture dir0[8]; h dies here
        float dir0[8];
        float pos = 0.f, vel = 0.f;
#pragma unroll
        for (int j = 0; j < 8; ++j) {
            float ht = fmaf(hr[j], csm, hd);
            float u  = fmaf(k, ht, fr[j]);
            dir0[j]  = ht - pos;
            float w  = fmaf(-k, pos, u);
            vel = (vel + w) * DAMP;
            pos += vel;
        }
        float Wx = pos, Wy = vel;

        // prefetch next chain
        float4 nf0, nf1, nh0, nh1;
        if (dit + 1 < 4) {
            size_t gn = gbase + NS;
            nf0 = *(const float4*)(forces + gn);
            nf1 = *(const float4*)(forces + gn + 4);
            nh0 = *(const float4*)(hm + gn);
            nh1 = *(const float4*)(hm + gn + 4);
        }

        Mat A   = {1.f - DAMP * k, DAMP, -DAMP * k, DAMP};
        Mat A2  = matmul(A, A);
        Mat A4  = matmul(A2, A2);
        Mat G0  = matmul(A4, A4);      // A^8
        Mat G1  = matmul(G0, G0);      // A^16
        Mat G2  = matmul(G1, G1);      // A^32
        Mat G3  = matmul(G2, G2);      // A^64
        Mat P = {1.f, 0.f, 0.f, 1.f};  // (A^8)^sub
        if (sub & 1) P = matmul(P, G0);
        if (sub & 2) P = matmul(P, G1);
        if (sub & 4) P = matmul(P, G2);
        if (sub & 8) P = matmul(P, G3);

        // 16-lane Kogge-Stone (f32) within chunk groups
        {
            float ox, oy;
            ox = __shfl_up(Wx, 1, 64); oy = __shfl_up(Wy, 1, 64);
            if (sub >= 1) { float nx = Wx + fmaf(G0.a, ox, G0.b * oy);
                            float ny = Wy + fmaf(G0.c, ox, G0.d * oy);
                            Wx = nx; Wy = ny; }
            ox = __shfl_up(Wx, 2, 64); oy = __shfl_up(Wy, 2, 64);
            if (sub >= 2) { float nx = Wx + fmaf(G1.a, ox, G1.b * oy);
                            float ny = Wy + fmaf(G1.c, ox, G1.d * oy);
                            Wx = nx; Wy = ny; }
            ox = __shfl_up(Wx, 4, 64); oy = __shfl_up(Wy, 4, 64);
            if (sub >= 4) { float nx = Wx + fmaf(G2.a, ox, G2.b * oy);
                            float ny = Wy + fmaf(G2.c, ox, G2.d * oy);
                            Wx = nx; Wy = ny; }
            ox = __shfl_up(Wx, 8, 64); oy = __shfl_up(Wy, 8, 64);
            if (sub >= 8) { float nx = Wx + fmaf(G3.a, ox, G3.b * oy);
                            float ny = Wy + fmaf(G3.c, ox, G3.d * oy);
                            Wx = nx; Wy = ny; }
        }
        float Ex = __shfl_up(Wx, 1, 64);
        float Ey = __shfl_up(Wy, 1, 64);
        if (sub == 0) { Ex = 0.f; Ey = 0.f; }
        if (sub == 15) qcL[dit & 1][tid >> 4] = make_float2(Wx, Wy);

        __syncthreads();   // one barrier per chain

        // f32 chunk scan over 64 chunks, redundantly per wave (lane = chunk)
        float s0x, s0y;
        {
            int lane = tid & 63;
            Mat B = matmul(G3, G3);     // A^128
            float2 qv = qcL[dit & 1][lane];
            float sx = qv.x, sy = qv.y;
            Mat Kr = B;
#pragma unroll
            for (int r = 0; r < 6; ++r) {
                float ox = __shfl_up(sx, 1 << r, 64);
                float oy = __shfl_up(sy, 1 << r, 64);
                if (lane >= (1 << r)) {
                    float nx = fmaf(Kr.a, ox, fmaf(Kr.b, oy, sx));
                    float ny = fmaf(Kr.c, ox, fmaf(Kr.d, oy, sy));
                    sx = nx; sy = ny;
                }
                if (r < 5) Kr = matmul(Kr, Kr);
            }
            int srcc = (tid >> 4) - 1;
            float px = __shfl(sx, srcc & 63, 64);
            float py = __shfl(sy, srcc & 63, 64);
            if (srcc < 0) { px = 0.f; py = 0.f; }
            s0x = px; s0y = py;
        }

        // window-start state, then linear correction pass
        float ex = fmaf(P.a, s0x, fmaf(P.b, s0y, Ex));
        float ey = fmaf(P.c, s0x, fmaf(P.d, s0y, Ey));

#pragma unroll
        for (int q = 0; q < 2; ++q) {
            float dv[4];
#pragma unroll
            for (int i = 0; i < 4; ++i) {
                int j = q * 4 + i;
                float dir = dir0[j] - ex;                 // dir = dir0 - [A^j s]x
                float acc = fmaf(k, dir, fr[j]);          // reference-exact
                dv[i] = dir;
                rec_acc[j] = fmaf(mm_, acc, rec_acc[j]);  // 4-chain partial
                float nx = fmaf(A.a, ex, A.b * ey);       // e <- A e
                float ny = fmaf(A.c, ex, A.d * ey);
                ex = nx; ey = ny;
            }
            *(float4*)(out + DISP_OFF + gbase + q * 4) =
                make_float4(dv[0], dv[1], dv[2], dv[3]);
        }

        if (dit + 1 < 4) {
            fq[0] = nf0; fq[1] = nf1;
            hq[0] = nh0; hq[1] = nh1;
        }
    }

    // write partial rec row (bh), coalesced
    size_t prow = (size_t)bh * NS + tid * 8;
    *(float4*)(part + prow) =
        make_float4(rec_acc[0], rec_acc[1], rec_acc[2], rec_acc[3]);
    *(float4*)(part + prow + 4) =
        make_float4(rec_acc[4], rec_acc[5], rec_acc[6], rec_acc[7]);
}

// ---------------- HF kernel: 2-partial sum + noise + FIR + rec/hf write -----
// Grid 1024 = 256 (b,m) x 4 segments of 2048.
__global__ __launch_bounds__(256) void hf_kernel(
    const float* __restrict__ part,
    const float* __restrict__ filters, const float* __restrict__ tfm,
    const float* __restrict__ bias,    const float* __restrict__ hf_gain,
    float* __restrict__ out)
{
    __shared__ float up[SW(FL + SEG) + 8];
    __shared__ float recL[SEG];
    __shared__ float gtap[FL];
    int bm  = blockIdx.x >> 2;
    int seg = blockIdx.x & 3;
    int b = bm >> 6;
    int m = bm & 63;
    int tx = threadIdx.x;
    int T0 = seg * SEG;

    float gs = 0.f;
#pragma unroll
    for (int f = 0; f < NF; ++f) {
        float mix = 0.f;
#pragma unroll
        for (int dd = 0; dd < DD; ++dd)
            mix = fmaf(bias[m * DD + dd], tfm[(m * DD + dd) * NF + f], mix);
        gs = fmaf(mix, filters[(b * NF + f) * FL + tx], gs);
    }
    gtap[tx] = gs;

    const float* p0 = part + (size_t)(bm * 2) * NS;
    const float* p1 = p0 + NS;
    for (int j = tx; j < FL + SEG; j += 256) {
        int t = T0 - FL + j;
        float v = 0.f, r = 0.f;
        if (t >= 0) {
            r = p0[t] + p1[t];
            v = fabsf(r) * jax_noise((unsigned)(bm * NS + t));
        }
        up[SW(j)] = v;
        if (j >= FL) recL[j - FL] = r;
    }
    __syncthreads();

    float gain = hf_gain[0];
    int t0 = tx * 8;
    float acc[8] = {0, 0, 0, 0, 0, 0, 0, 0};
    float w[8];
#pragma unroll
    for (int j = 0; j < 8; ++j) w[j] = up[SW(t0 + 1 + j)];
#pragma unroll 8
    for (int s = 255; s >= 1; --s) {
        float gv = gtap[s];
#pragma unroll
        for (int j = 0; j < 8; ++j) acc[j] = fmaf(gv, w[j], acc[j]);
#pragma unroll
        for (int j = 0; j < 7; ++j) w[j] = w[j + 1];
        w[7] = up[SW(FL + t0 + 8 - s)];
    }
    float g0 = gtap[0];
#pragma unroll
    for (int j = 0; j < 8; ++j) acc[j] = fmaf(g0, w[j], acc[j]);
    float4 r0 = *(const float4*)(&recL[t0]);
    float4 r1 = *(const float4*)(&recL[t0 + 4]);
    float4 o0 = make_float4(fmaf(gain, acc[0], r0.x), fmaf(gain, acc[1], r0.y),
                            fmaf(gain, acc[2], r0.z), fmaf(gain, acc[3], r0.w));
    float4 o1 = make_float4(fmaf(gain, acc[4], r1.x), fmaf(gain, acc[5], r1.y),
                            fmaf(gain, acc[6], r1.z), fmaf(gain, acc[7], r1.w));
    size_t rowoff = (size_t)bm * NS + T0 + t0;
    *(float4*)(out + HF_OFF + rowoff)     = o0;
    *(float4*)(out + HF_OFF + rowoff + 4) = o1;
    *(float4*)(out + REC_OFF + rowoff)     = r0;
    *(float4*)(out + REC_OFF + rowoff + 4) = r1;
}

extern "C" void kernel_launch(void* const* d_in, const int* in_sizes, int n_in,
                              void* d_out, int out_size, void* d_ws, size_t ws_size,
                              hipStream_t stream)
{
    const float* forces  = (const float*)d_in[0];
    const float* hm      = (const float*)d_in[1];
    const float* filters = (const float*)d_in[2];
    const float* home    = (const float*)d_in[3];
    const float* cs      = (const float*)d_in[4];
    const float* masses  = (const float*)d_in[5];
    const float* tens    = (const float*)d_in[6];
    const float* mics    = (const float*)d_in[7];
    const float* tfm     = (const float*)d_in[8];
    const float* bias    = (const float*)d_in[9];
    const float* gain    = (const float*)d_in[10];
    float* out = (float*)d_out;

    float* part = (float*)d_ws;    // 512 rows x 8192 floats = 16 MiB

    sim_half<<<BB * MM * 2, 1024, 0, stream>>>(
        forces, hm, home, cs, masses, tens, mics, out, part);
    hf_kernel<<<BB * MM * 4, 256, 0, stream>>>(
        part, filters, tfm, bias, gain, out);
}

// Round 20
// 65.092 us; speedup vs baseline: 2.3172x; 1.1419x over previous
//
#include <hip/hip_runtime.h>

// ---------------------------------------------------------------------------
// BetterGooLayer R20 (final): revert to R17 — the measured best (64.8 us).
// Roofline: harness hipMemsetAsync(d_out)=327MB ~48us (fixed, in timed graph)
// + kernel net ~17us vs ~16.3us VALU-issue floor (4900 ops/thread x 2cyc x
// 4 waves/SIMD @ 2.4GHz) -> within ~1% of the combined floor.
// R18 (pairing) and R19 (occupancy split) both regressed; R17 structure:
// block = bm, 8-chain loop, thread owns [tid*8,tid*8+8) for all chains ->
// rec d-reduction in registers; FIR fused in-block; one kernel, no scratch.
// ---------------------------------------------------------------------------

#define NS    8192
#define BB    4
#define MM    64
#define DD    8
#define NF    8
#define FL    256
#define DAMP  0.9998f

#define REC_OFF  0
#define DISP_OFF (BB*MM*NS)                 // 2097152
#define HF_OFF   (DISP_OFF + BB*MM*DD*NS)   // 18874368

#define SW(i) ((i) + ((i) >> 5))

struct Mat { float a, b, c, d; };
__device__ __forceinline__ Mat matmul(Mat x, Mat y) {
    Mat r;
    r.a = fmaf(x.a, y.a, x.b * y.c);
    r.b = fmaf(x.a, y.b, x.b * y.d);
    r.c = fmaf(x.c, y.a, x.d * y.c);
    r.d = fmaf(x.c, y.b, x.d * y.d);
    return r;
}

// ---------------- threefry2x32 (JAX, partitionable counters) ----------------
__device__ __forceinline__ unsigned rotl32(unsigned x, int r) {
    return (x << r) | (x >> (32 - r));
}
__device__ float jax_noise(unsigned idx) {
    const unsigned ks0 = 0u;
    const unsigned ks1 = 123u;
    const unsigned ks2 = 0x1BD11BDAu ^ 0u ^ 123u;
    unsigned x0 = 0u  + ks0;
    unsigned x1 = idx + ks1;
#define TF_RND(r) { x0 += x1; x1 = rotl32(x1, r); x1 ^= x0; }
    TF_RND(13) TF_RND(15) TF_RND(26) TF_RND(6)
    x0 += ks1; x1 += ks2 + 1u;
    TF_RND(17) TF_RND(29) TF_RND(16) TF_RND(24)
    x0 += ks2; x1 += ks0 + 2u;
    TF_RND(13) TF_RND(15) TF_RND(26) TF_RND(6)
    x0 += ks0; x1 += ks1 + 3u;
    TF_RND(17) TF_RND(29) TF_RND(16) TF_RND(24)
    x0 += ks1; x1 += ks2 + 4u;
    TF_RND(13) TF_RND(15) TF_RND(26) TF_RND(6)
    x0 += ks2; x1 += ks0 + 5u;
#undef TF_RND
    unsigned bits = x0 ^ x1;
    float u = __uint_as_float((bits >> 9) | 0x3f800000u) - 1.0f;  // [0,1)
    return fmaxf(-0.01f, u * 0.02f - 0.01f);
}

// ---------------- fused everything: block = bm, 1024 threads ----------------
__global__ __launch_bounds__(1024, 4) void sim_all(
    const float* __restrict__ forces, const float* __restrict__ hm,
    const float* __restrict__ home,   const float* __restrict__ cs,
    const float* __restrict__ masses, const float* __restrict__ tens,
    const float* __restrict__ mics,
    const float* __restrict__ filters, const float* __restrict__ tfm,
    const float* __restrict__ bias,    const float* __restrict__ hf_gain,
    float* __restrict__ out)
{
    __shared__ float up[SW(FL + NS) + 8];   // ~34.8 KB noise window
    __shared__ float gtap[FL];
    __shared__ float2 qcL[2][64];

    int bm   = blockIdx.x;
    int tid  = threadIdx.x;
    int sub  = tid & 15;            // position within 16-thread chunk group
    int m    = bm & (MM - 1);

    float ms  = masses[m];
    float csm = cs[m];

    size_t chbase = (size_t)(bm * DD) * NS + tid * 8;

    float rec_acc[8] = {0, 0, 0, 0, 0, 0, 0, 0};

    // prologue: chain 0 loads
    float4 fq[2], hq[2];
    fq[0] = *(const float4*)(forces + chbase);
    fq[1] = *(const float4*)(forces + chbase + 4);
    hq[0] = *(const float4*)(hm + chbase);
    hq[1] = *(const float4*)(hm + chbase + 4);

    for (int d = 0; d < DD; ++d) {
        float k   = tens[m * DD + d] / ms;
        float hd  = home[d];
        float mm_ = ms * mics[m * DD + d];
        size_t gbase = chbase + (size_t)d * NS;

        const float* fr = (const float*)fq;
        const float* hr = (const float*)hq;

        // walk1 from zero state (u-form), capture dir0[8]; h dies here
        float dir0[8];
        float pos = 0.f, vel = 0.f;
#pragma unroll
        for (int j = 0; j < 8; ++j) {
            float ht = fmaf(hr[j], csm, hd);
            float u  = fmaf(k, ht, fr[j]);
            dir0[j]  = ht - pos;
            float w  = fmaf(-k, pos, u);
            vel = (vel + w) * DAMP;
            pos += vel;
        }
        float Wx = pos, Wy = vel;

        // prefetch next chain (hq dead; fq still live for correction)
        float4 nf0, nf1, nh0, nh1;
        if (d + 1 < DD) {
            size_t gn = gbase + NS;
            nf0 = *(const float4*)(forces + gn);
            nf1 = *(const float4*)(forces + gn + 4);
            nh0 = *(const float4*)(hm + gn);
            nh1 = *(const float4*)(hm + gn + 4);
        }

        Mat A   = {1.f - DAMP * k, DAMP, -DAMP * k, DAMP};
        Mat A2  = matmul(A, A);
        Mat A4  = matmul(A2, A2);
        Mat G0  = matmul(A4, A4);      // A^8
        Mat G1  = matmul(G0, G0);      // A^16
        Mat G2  = matmul(G1, G1);      // A^32
        Mat G3  = matmul(G2, G2);      // A^64
        Mat P = {1.f, 0.f, 0.f, 1.f};  // (A^8)^sub
        if (sub & 1) P = matmul(P, G0);
        if (sub & 2) P = matmul(P, G1);
        if (sub & 4) P = matmul(P, G2);
        if (sub & 8) P = matmul(P, G3);

        // 16-lane Kogge-Stone (f32) within chunk groups
        {
            float ox, oy;
            ox = __shfl_up(Wx, 1, 64); oy = __shfl_up(Wy, 1, 64);
            if (sub >= 1) { float nx = Wx + fmaf(G0.a, ox, G0.b * oy);
                            float ny = Wy + fmaf(G0.c, ox, G0.d * oy);
                            Wx = nx; Wy = ny; }
            ox = __shfl_up(Wx, 2, 64); oy = __shfl_up(Wy, 2, 64);
            if (sub >= 2) { float nx = Wx + fmaf(G1.a, ox, G1.b * oy);
                            float ny = Wy + fmaf(G1.c, ox, G1.d * oy);
                            Wx = nx; Wy = ny; }
            ox = __shfl_up(Wx, 4, 64); oy = __shfl_up(Wy, 4, 64);
            if (sub >= 4) { float nx = Wx + fmaf(G2.a, ox, G2.b * oy);
                            float ny = Wy + fmaf(G2.c, ox, G2.d * oy);
                            Wx = nx; Wy = ny; }
            ox = __shfl_up(Wx, 8, 64); oy = __shfl_up(Wy, 8, 64);
            if (sub >= 8) { float nx = Wx + fmaf(G3.a, ox, G3.b * oy);
                            float ny = Wy + fmaf(G3.c, ox, G3.d * oy);
                            Wx = nx; Wy = ny; }
        }
        float Ex = __shfl_up(Wx, 1, 64);
        float Ey = __shfl_up(Wy, 1, 64);
        if (sub == 0) { Ex = 0.f; Ey = 0.f; }
        if (sub == 15) qcL[d & 1][tid >> 4] = make_float2(Wx, Wy);

        __syncthreads();   // one barrier per chain

        // f32 chunk scan over 64 chunks, redundantly per wave (lane = chunk)
        float s0x, s0y;
        {
            int lane = tid & 63;
            Mat B = matmul(G3, G3);     // A^128
            float2 qv = qcL[d & 1][lane];
            float sx = qv.x, sy = qv.y;
            Mat Kr = B;
#pragma unroll
            for (int r = 0; r < 6; ++r) {
                float ox = __shfl_up(sx, 1 << r, 64);
                float oy = __shfl_up(sy, 1 << r, 64);
                if (lane >= (1 << r)) {
                    float nx = fmaf(Kr.a, ox, fmaf(Kr.b, oy, sx));
                    float ny = fmaf(Kr.c, ox, fmaf(Kr.d, oy, sy));
                    sx = nx; sy = ny;
                }
                if (r < 5) Kr = matmul(Kr, Kr);
            }
            int srcc = (tid >> 4) - 1;
            float px = __shfl(sx, srcc & 63, 64);
            float py = __shfl(sy, srcc & 63, 64);
            if (srcc < 0) { px = 0.f; py = 0.f; }
            s0x = px; s0y = py;
        }

        // window-start state, then linear correction pass
        float ex = fmaf(P.a, s0x, fmaf(P.b, s0y, Ex));
        float ey = fmaf(P.c, s0x, fmaf(P.d, s0y, Ey));

#pragma unroll
        for (int q = 0; q < 2; ++q) {
            float dv[4];
#pragma unroll
            for (int i = 0; i < 4; ++i) {
                int j = q * 4 + i;
                float dir = dir0[j] - ex;                 // dir = dir0 - [A^j s]x
                float acc = fmaf(k, dir, fr[j]);          // reference-exact
                dv[i] = dir;
                rec_acc[j] = fmaf(mm_, acc, rec_acc[j]);  // d-reduction in regs
                float nx = fmaf(A.a, ex, A.b * ey);       // e <- A e
                float ny = fmaf(A.c, ex, A.d * ey);
                ex = nx; ey = ny;
            }
            *(float4*)(out + DISP_OFF + gbase + q * 4) =
                make_float4(dv[0], dv[1], dv[2], dv[3]);
        }

        if (d + 1 < DD) {
            fq[0] = nf0; fq[1] = nf1;
            hq[0] = nh0; hq[1] = nh1;
        }
    }

    // ---- rec output + noise window + combined filter taps ----
    size_t rowbase = (size_t)bm * NS + tid * 8;
    *(float4*)(out + REC_OFF + rowbase) =
        make_float4(rec_acc[0], rec_acc[1], rec_acc[2], rec_acc[3]);
    *(float4*)(out + REC_OFF + rowbase + 4) =
        make_float4(rec_acc[4], rec_acc[5], rec_acc[6], rec_acc[7]);

    int t0 = tid * 8;
#pragma unroll
    for (int i = 0; i < 8; ++i) {
        float nz = jax_noise((unsigned)(bm * NS + t0 + i));
        up[SW(FL + t0 + i)] = fabsf(rec_acc[i]) * nz;
    }
    if (tid < FL) {
        up[SW(tid)] = 0.f;     // left pad (t < 0)
        int b = bm >> 6;
        float gs = 0.f;
#pragma unroll
        for (int f = 0; f < NF; ++f) {
            float mix = 0.f;
#pragma unroll
            for (int dd = 0; dd < DD; ++dd)
                mix = fmaf(bias[m * DD + dd], tfm[(m * DD + dd) * NF + f], mix);
            gs = fmaf(mix, filters[(b * NF + f) * FL + tid], gs);
        }
        gtap[tid] = gs;
    }
    __syncthreads();

    // ---- FIR: 8 outputs per thread, register sliding window ----
    float gain = hf_gain[0];
    float acc[8] = {0, 0, 0, 0, 0, 0, 0, 0};
    float w[8];
#pragma unroll
    for (int j = 0; j < 8; ++j) w[j] = up[SW(t0 + 1 + j)];
#pragma unroll 8
    for (int s = 255; s >= 1; --s) {
        float gv = gtap[s];
#pragma unroll
        for (int j = 0; j < 8; ++j) acc[j] = fmaf(gv, w[j], acc[j]);
#pragma unroll
        for (int j = 0; j < 7; ++j) w[j] = w[j + 1];
        w[7] = up[SW(FL + t0 + 8 - s)];
    }
    float g0 = gtap[0];
#pragma unroll
    for (int j = 0; j < 8; ++j) acc[j] = fmaf(g0, w[j], acc[j]);
    float4 o0 = make_float4(fmaf(gain, acc[0], rec_acc[0]),
                            fmaf(gain, acc[1], rec_acc[1]),
                            fmaf(gain, acc[2], rec_acc[2]),
                            fmaf(gain, acc[3], rec_acc[3]));
    float4 o1 = make_float4(fmaf(gain, acc[4], rec_acc[4]),
                            fmaf(gain, acc[5], rec_acc[5]),
                            fmaf(gain, acc[6], rec_acc[6]),
                            fmaf(gain, acc[7], rec_acc[7]));
    *(float4*)(out + HF_OFF + rowbase)     = o0;
    *(float4*)(out + HF_OFF + rowbase + 4) = o1;
}

extern "C" void kernel_launch(void* const* d_in, const int* in_sizes, int n_in,
                              void* d_out, int out_size, void* d_ws, size_t ws_size,
                              hipStream_t stream)
{
    const float* forces  = (const float*)d_in[0];
    const float* hm      = (const float*)d_in[1];
    const float* filters = (const float*)d_in[2];
    const float* home    = (const float*)d_in[3];
    const float* cs      = (const float*)d_in[4];
    const float* masses  = (const float*)d_in[5];
    const float* tens    = (const float*)d_in[6];
    const float* mics    = (const float*)d_in[7];
    const float* tfm     = (const float*)d_in[8];
    const float* bias    = (const float*)d_in[9];
    const float* gain    = (const float*)d_in[10];
    float* out = (float*)d_out;

    sim_all<<<BB * MM, 1024, 0, stream>>>(
        forces, hm, home, cs, masses, tens, mics,
        filters, tfm, bias, gain, out);
}